// Round 10
// baseline (138.145 us; speedup 1.0000x reference)
//
#include <hip/hip_runtime.h>
#include <cfloat>

typedef unsigned long long ull;
typedef int v2i __attribute__((ext_vector_type(2)));

constexpr int BDIM = 256;
constexpr int NPTS = 8192;
constexpr int KSEL = 16;
constexpr int PD_  = 16;
constexpr int DIN  = 20;
constexpr int HID  = 128;
constexpr int DOUT = 256;
constexpr int CAP  = 384;      // candidate capacity (E[cnt] ~ 40-80)
constexpr int ROWS = 2;        // rows per block (sequential -> 2 generations)

__device__ __forceinline__ ull mkkey(float d, int n) {
    // positive-float bits are order-monotone; low 32 bits = index (tie-break)
    return ((ull)__float_as_uint(d) << 32) | (unsigned int)n;
}

// ---------- f32 wave butterfly min (DPP + 1 ds_swizzle + permlane32) --------
template<int CTRL>
__device__ __forceinline__ float dppmin_f32(float v) {
    const int o = __builtin_amdgcn_mov_dpp(__float_as_int(v), CTRL, 0xF, 0xF, true);
    return fminf(v, __int_as_float(o));
}
__device__ __forceinline__ float swz16min_f32(float v) {
    const int o = __builtin_amdgcn_ds_swizzle(__float_as_int(v), 0x401F); // xor16
    return fminf(v, __int_as_float(o));
}
__device__ __forceinline__ float half32min_f32(float v, int lane) {
#if __has_builtin(__builtin_amdgcn_permlane32_swap)
    v2i r = __builtin_amdgcn_permlane32_swap(__float_as_int(v), __float_as_int(v), false, false);
    const int o = (lane < 32) ? r[1] : r[0];
#else
    const int o = __shfl_xor(__float_as_int(v), 32, 64);
#endif
    return fminf(v, __int_as_float(o));
}
__device__ __forceinline__ float wavemin_f32(float v, int lane) {
    v = dppmin_f32<0xB1>(v);    // quad_perm xor1
    v = dppmin_f32<0x4E>(v);    // quad_perm xor2
    v = dppmin_f32<0x124>(v);   // row_ror:4
    v = dppmin_f32<0x128>(v);   // row_ror:8
    v = swz16min_f32(v);        // xor16
    v = half32min_f32(v, lane); // cross-32
    return v;
}

// ---- ONE kernel, 2 rows/block: stream + top-16 + gather + feature + MLP ---
__global__ __launch_bounds__(BDIM, 4) void encoder_kernel(
    const float* __restrict__ lg,      // (2,)
    const float* __restrict__ coords,  // (B, N, 3)
    const float* __restrict__ params,  // (B, N, 16)
    const float* __restrict__ W1, const float* __restrict__ b1,
    const float* __restrict__ W2, const float* __restrict__ b2,
    const float* __restrict__ W3, const float* __restrict__ b3,
    float* __restrict__ out)           // (B, 256)
{
    __shared__ float twave[4];
    __shared__ ull   cand[CAP];
    __shared__ int   ccnt;
    __shared__ int   selb[KSEL];
    __shared__ float pbuf[KSEL][PD_ + 1];
    __shared__ float cbuf[KSEL][2];
    __shared__ float xvec[DIN];
    __shared__ float h1s[HID];
    __shared__ float h2p[2][HID];
    __shared__ float h2s[HID];

    const int tid  = threadIdx.x;
    const int lane = tid & 63;
    const int wid  = tid >> 6;
    const float lg0 = lg[0];
    const float lg1 = lg[1];

    for (int rr = 0; rr < ROWS; ++rr) {
        const int row = blockIdx.x * ROWS + rr;
        if (tid == 0) ccnt = 0;   // ordered before 2c atomics by 2b's barrier

        // ---- Phase 1: distances for 32 points/thread, f32 registers ----
        const float4* c4 =
            reinterpret_cast<const float4*>(coords + (size_t)row * NPTS * 3);
        float dd[32];
        #pragma unroll
        for (int it = 0; it < 8; ++it) {
            const int g = it * BDIM + tid;
            const float4 qa = c4[3 * g + 0];
            const float4 qb = c4[3 * g + 1];
            const float4 qc = c4[3 * g + 2];
            const float px[4] = {qa.x, qa.w, qb.z, qc.y};
            const float py[4] = {qa.y, qb.x, qb.w, qc.z};
            #pragma unroll
            for (int j = 0; j < 4; ++j) {
                // match numpy rounding: sub,sub,mul,mul,add — no fma contraction
                const float t0 = __fsub_rn(lg0, px[j]);
                const float t1 = __fsub_rn(lg1, py[j]);
                dd[it * 4 + j] = __fadd_rn(__fmul_rn(t0, t0), __fmul_rn(t1, t1));
            }
        }
        // global point index of slot (it,j): (it<<10) + (tid<<2) + j

        // ---- Phase 2a: per-thread min (register tree) ----
        float m;
        {
            float t[16];
            #pragma unroll
            for (int l = 0; l < 16; ++l) t[l] = fminf(dd[2 * l], dd[2 * l + 1]);
            #pragma unroll
            for (int s = 8; s > 0; s >>= 1)
                #pragma unroll
                for (int l = 0; l < 16; ++l) if (l < s) t[l] = fminf(t[l], t[l + s]);
            m = t[0];
        }

        // ---- Phase 2b: per-wave 4th-smallest; T = max over waves ----
        // (each wave then has >=4 thread-mins <= T -> >=16 points <= T;
        //  tie-collapse only raises T = safe superset)
        float tw;
        {
            float loc = m;
            #pragma unroll
            for (int r = 0; r < 4; ++r) {
                const float wmin = wavemin_f32(loc, lane);
                if (r == 3) { tw = wmin; break; }
                if (loc == wmin) loc = FLT_MAX;
            }
        }
        if (lane == 0) twave[wid] = tw;
        __syncthreads();
        const float T = fmaxf(fmaxf(twave[0], twave[1]), fmaxf(twave[2], twave[3]));

        // ---- Phase 2c: candidates with d <= T (contains all top-16) ----
        #pragma unroll
        for (int it = 0; it < 8; ++it) {
            #pragma unroll
            for (int j = 0; j < 4; ++j) {
                const float d = dd[it * 4 + j];
                if (d <= T) {
                    const int pos = atomicAdd(&ccnt, 1);
                    if (pos < CAP)
                        cand[pos] = mkkey(d, (it << 10) + (tid << 2) + j);
                }
            }
        }
        __syncthreads();

        // ---- Phase 2d: exact top-16 by rank (unique keys -> rank exact) ----
        if (wid == 0) {
            int cc = ccnt; if (cc > CAP) cc = CAP;
            for (int s = lane; s < cc; s += 64) {
                const ull k = cand[s];
                int rank = 0;
                for (int j = 0; j < cc; ++j) rank += (cand[j] < k);
                if (rank < KSEL) selb[rank] = (int)(unsigned)k;
            }
        }
        __syncthreads();

        // ---- Phase 3: coalesced gather of the 16 neighbor rows ----
        {   // params: 256 threads = 16 neighbors x 16 dims
            const int k = tid >> 4, p = tid & 15;
            pbuf[k][p] = params[((size_t)row * NPTS + selb[k]) * PD_ + p];
        }
        if (tid < 2 * KSEL) {
            const int k = tid >> 1, c = tid & 1;
            cbuf[k][c] = coords[((size_t)row * NPTS + selb[k]) * 3 + c];
        }
        __syncthreads();

        if (tid < DIN) {
            float v;
            if (tid < 2) {
                v = lg[tid];
            } else if (tid < 4) {
                float s = 0.f;
                for (int k = 0; k < KSEL; ++k) s += cbuf[k][tid - 2];
                v = s * (1.f / 16.f);
            } else {
                float s = 0.f;
                for (int k = 0; k < KSEL; ++k) s += pbuf[k][tid - 4];
                v = s * (1.f / 16.f);
            }
            xvec[tid] = v;
        }
        __syncthreads();

        // ---- Phase 4: MLP 20 -> 128 -> 128 -> 256 ----
        if (tid < HID) {
            float acc = b1[tid];
            #pragma unroll
            for (int i = 0; i < DIN; ++i) acc = fmaf(xvec[i], W1[i * HID + tid], acc);
            h1s[tid] = fmaxf(acc, 0.f);
        }
        __syncthreads();
        {   // layer 2 split across all 256 threads: 2 halves of the i-range
            const int half = tid >> 7;          // 0/1
            const int col  = tid & 127;
            float acc = (half == 0) ? b2[col] : 0.f;
            const int i0 = half * 64;
            #pragma unroll 16
            for (int ii = 0; ii < 64; ++ii) {
                const int i = i0 + ii;
                acc = fmaf(h1s[i], W2[i * HID + col], acc);
            }
            h2p[half][col] = acc;
        }
        __syncthreads();
        if (tid < HID) h2s[tid] = fmaxf(h2p[0][tid] + h2p[1][tid], 0.f);
        __syncthreads();
        {
            float acc = b3[tid];
            #pragma unroll 16
            for (int i = 0; i < HID; ++i) acc = fmaf(h2s[i], W3[i * DOUT + tid], acc);
            out[(size_t)row * DOUT + tid] = acc;
        }
        __syncthreads();   // protect LDS reuse before next row
    }
}

extern "C" void kernel_launch(void* const* d_in, const int* in_sizes, int n_in,
                              void* d_out, int out_size, void* d_ws, size_t ws_size,
                              hipStream_t stream) {
    const float* lg     = (const float*)d_in[0];
    const float* coords = (const float*)d_in[1];
    const float* params = (const float*)d_in[2];
    const float* W1     = (const float*)d_in[3];
    const float* b1     = (const float*)d_in[4];
    const float* W2     = (const float*)d_in[5];
    const float* b2     = (const float*)d_in[6];
    const float* W3     = (const float*)d_in[7];
    const float* b3     = (const float*)d_in[8];
    float* out          = (float*)d_out;

    const int Brows = in_sizes[1] / (NPTS * 3);  // 1024
    encoder_kernel<<<dim3(Brows / ROWS), dim3(BDIM), 0, stream>>>(
        lg, coords, params, W1, b1, W2, b2, W3, b3, out);
}

// Round 11
// 29.624 us; speedup vs baseline: 4.6633x; 4.6633x over previous
//
#include <hip/hip_runtime.h>
#include <cfloat>

typedef unsigned long long ull;
typedef int v2i __attribute__((ext_vector_type(2)));

constexpr int BDIM = 512;      // 2 row-groups x 256 threads
constexpr int TPR  = 256;      // threads per row
constexpr int NPTS = 8192;
constexpr int KSEL = 16;
constexpr int PD_  = 16;
constexpr int DIN  = 20;
constexpr int HID  = 128;
constexpr int DOUT = 256;
constexpr int CAP  = 384;      // candidate capacity per row (E[cnt] ~ 40-80)

__device__ __forceinline__ ull mkkey(float d, int n) {
    // positive-float bits are order-monotone; low 32 bits = index (tie-break)
    return ((ull)__float_as_uint(d) << 32) | (unsigned int)n;
}

// ---------- f32 wave butterfly min (DPP + 1 ds_swizzle + permlane32) --------
template<int CTRL>
__device__ __forceinline__ float dppmin_f32(float v) {
    const int o = __builtin_amdgcn_mov_dpp(__float_as_int(v), CTRL, 0xF, 0xF, true);
    return fminf(v, __int_as_float(o));
}
__device__ __forceinline__ float swz16min_f32(float v) {
    const int o = __builtin_amdgcn_ds_swizzle(__float_as_int(v), 0x401F); // xor16
    return fminf(v, __int_as_float(o));
}
__device__ __forceinline__ float half32min_f32(float v, int lane) {
#if __has_builtin(__builtin_amdgcn_permlane32_swap)
    v2i r = __builtin_amdgcn_permlane32_swap(__float_as_int(v), __float_as_int(v), false, false);
    const int o = (lane < 32) ? r[1] : r[0];
#else
    const int o = __shfl_xor(__float_as_int(v), 32, 64);
#endif
    return fminf(v, __int_as_float(o));
}
__device__ __forceinline__ float wavemin_f32(float v, int lane) {
    v = dppmin_f32<0xB1>(v);    // quad_perm xor1
    v = dppmin_f32<0x4E>(v);    // quad_perm xor2
    v = dppmin_f32<0x124>(v);   // row_ror:4
    v = dppmin_f32<0x128>(v);   // row_ror:8
    v = swz16min_f32(v);        // xor16
    v = half32min_f32(v, lane); // cross-32
    return v;
}

// ---- ONE kernel, 2 rows/block in PARALLEL (waves 0-3 row A, 4-7 row B) ----
__global__ __launch_bounds__(BDIM, 4) void encoder_kernel(
    const float* __restrict__ lg,      // (2,)
    const float* __restrict__ coords,  // (B, N, 3)
    const float* __restrict__ params,  // (B, N, 16)
    const float* __restrict__ W1, const float* __restrict__ b1,
    const float* __restrict__ W2, const float* __restrict__ b2,
    const float* __restrict__ W3, const float* __restrict__ b3,
    float* __restrict__ out)           // (B, 256)
{
    __shared__ float twave[8];
    __shared__ ull   cand[2][CAP];
    __shared__ int   ccnt[2];
    __shared__ int   selb[2][KSEL];
    __shared__ float pbuf[2][KSEL][PD_ + 1];
    __shared__ float cbuf[2][KSEL][2];
    __shared__ float xvec[2][DIN];
    __shared__ float h1s[2][HID];
    __shared__ float h2p[2][2][HID];
    __shared__ float h2s[2][HID];

    const int tid  = threadIdx.x;
    const int lane = tid & 63;
    const int wid  = tid >> 6;          // 0..7
    const int rg   = tid >> 8;          // row group 0/1
    const int t    = tid & (TPR - 1);   // thread id within row group
    const int row  = blockIdx.x * 2 + rg;
    const float lg0 = lg[0];
    const float lg1 = lg[1];

    if (tid == 0) { ccnt[0] = 0; ccnt[1] = 0; }

    // ---- Phase 1: distances for 32 points/thread, f32 registers ----
    const float4* c4 = reinterpret_cast<const float4*>(coords + (size_t)row * NPTS * 3);
    float dd[32];
    #pragma unroll
    for (int it = 0; it < 8; ++it) {
        const int g = it * TPR + t;
        const float4 qa = c4[3 * g + 0];
        const float4 qb = c4[3 * g + 1];
        const float4 qc = c4[3 * g + 2];
        const float px[4] = {qa.x, qa.w, qb.z, qc.y};
        const float py[4] = {qa.y, qb.x, qb.w, qc.z};
        #pragma unroll
        for (int j = 0; j < 4; ++j) {
            // match numpy rounding: sub, sub, mul, mul, add — no fma contraction
            const float t0 = __fsub_rn(lg0, px[j]);
            const float t1 = __fsub_rn(lg1, py[j]);
            dd[it * 4 + j] = __fadd_rn(__fmul_rn(t0, t0), __fmul_rn(t1, t1));
        }
    }
    // point index of slot (it,j) within row: (it<<10) + (t<<2) + j

    // ---- Phase 2a: per-thread min (register tree) ----
    float m;
    {
        float tt[16];
        #pragma unroll
        for (int l = 0; l < 16; ++l) tt[l] = fminf(dd[2 * l], dd[2 * l + 1]);
        #pragma unroll
        for (int s = 8; s > 0; s >>= 1)
            #pragma unroll
            for (int l = 0; l < 16; ++l) if (l < s) tt[l] = fminf(tt[l], tt[l + s]);
        m = tt[0];
    }

    // ---- Phase 2b: per-wave 4th-smallest; T = max over the row's 4 waves ----
    // (each of the row's 4 waves then has >=4 thread-mins <= T -> >=16 points;
    //  tie-collapse only raises T = safe superset)
    float tw;
    {
        float loc = m;
        #pragma unroll
        for (int r = 0; r < 4; ++r) {
            const float wmin = wavemin_f32(loc, lane);
            if (r == 3) { tw = wmin; break; }
            if (loc == wmin) loc = FLT_MAX;
        }
    }
    if (lane == 0) twave[wid] = tw;
    __syncthreads();
    const float T = fmaxf(fmaxf(twave[rg * 4 + 0], twave[rg * 4 + 1]),
                          fmaxf(twave[rg * 4 + 2], twave[rg * 4 + 3]));

    // ---- Phase 2c: candidates with d <= T (contains all top-16 of the row) --
    #pragma unroll
    for (int it = 0; it < 8; ++it) {
        #pragma unroll
        for (int j = 0; j < 4; ++j) {
            const float d = dd[it * 4 + j];
            if (d <= T) {
                const int pos = atomicAdd(&ccnt[rg], 1);
                if (pos < CAP)
                    cand[rg][pos] = mkkey(d, (it << 10) + (t << 2) + j);
            }
        }
    }
    __syncthreads();

    // ---- Phase 2d: exact top-16 by rank (unique keys -> rank exact) ----
    if ((wid & 3) == 0) {               // wave 0 -> row 0, wave 4 -> row 1
        const int rr = wid >> 2;
        int cc = ccnt[rr]; if (cc > CAP) cc = CAP;
        for (int s = lane; s < cc; s += 64) {
            const ull k = cand[rr][s];
            int rank = 0;
            for (int j = 0; j < cc; ++j) rank += (cand[rr][j] < k);
            if (rank < KSEL) selb[rr][rank] = (int)(unsigned)k;
        }
    }
    __syncthreads();

    // ---- Phase 3: coalesced gather of the 16 neighbor rows (per row) ----
    {   // params: 256 threads/row = 16 neighbors x 16 dims
        const int k = t >> 4, p = t & 15;
        pbuf[rg][k][p] = params[((size_t)row * NPTS + selb[rg][k]) * PD_ + p];
    }
    if (t < 2 * KSEL) {
        const int k = t >> 1, c = t & 1;
        cbuf[rg][k][c] = coords[((size_t)row * NPTS + selb[rg][k]) * 3 + c];
    }
    __syncthreads();

    if (t < DIN) {
        float v;
        if (t < 2) {
            v = lg[t];
        } else if (t < 4) {
            float s = 0.f;
            for (int k = 0; k < KSEL; ++k) s += cbuf[rg][k][t - 2];
            v = s * (1.f / 16.f);
        } else {
            float s = 0.f;
            for (int k = 0; k < KSEL; ++k) s += pbuf[rg][k][t - 4];
            v = s * (1.f / 16.f);
        }
        xvec[rg][t] = v;
    }
    __syncthreads();

    // ---- Phase 4: MLP for BOTH rows on threads 0-255, shared weight reads --
    if (tid < HID) {
        float a0 = b1[tid], a1 = a0;
        #pragma unroll
        for (int i = 0; i < DIN; ++i) {
            const float w = W1[i * HID + tid];
            a0 = fmaf(xvec[0][i], w, a0);
            a1 = fmaf(xvec[1][i], w, a1);
        }
        h1s[0][tid] = fmaxf(a0, 0.f);
        h1s[1][tid] = fmaxf(a1, 0.f);
    }
    __syncthreads();
    if (tid < 2 * HID) {   // layer 2: 256 threads = 2 i-halves x 128 cols
        const int halfk = tid >> 7;
        const int col   = tid & 127;
        float a0 = (halfk == 0) ? b2[col] : 0.f, a1 = a0;
        const int i0 = halfk * 64;
        #pragma unroll 16
        for (int ii = 0; ii < 64; ++ii) {
            const int i = i0 + ii;
            const float w = W2[i * HID + col];
            a0 = fmaf(h1s[0][i], w, a0);
            a1 = fmaf(h1s[1][i], w, a1);
        }
        h2p[0][halfk][col] = a0;
        h2p[1][halfk][col] = a1;
    }
    __syncthreads();
    if (tid < HID) {
        h2s[0][tid] = fmaxf(h2p[0][0][tid] + h2p[0][1][tid], 0.f);
        h2s[1][tid] = fmaxf(h2p[1][0][tid] + h2p[1][1][tid], 0.f);
    }
    __syncthreads();
    if (tid < DOUT) {
        float a0 = b3[tid], a1 = a0;
        #pragma unroll 16
        for (int i = 0; i < HID; ++i) {
            const float w = W3[i * DOUT + tid];
            a0 = fmaf(h2s[0][i], w, a0);
            a1 = fmaf(h2s[1][i], w, a1);
        }
        out[((size_t)blockIdx.x * 2 + 0) * DOUT + tid] = a0;
        out[((size_t)blockIdx.x * 2 + 1) * DOUT + tid] = a1;
    }
}

extern "C" void kernel_launch(void* const* d_in, const int* in_sizes, int n_in,
                              void* d_out, int out_size, void* d_ws, size_t ws_size,
                              hipStream_t stream) {
    const float* lg     = (const float*)d_in[0];
    const float* coords = (const float*)d_in[1];
    const float* params = (const float*)d_in[2];
    const float* W1     = (const float*)d_in[3];
    const float* b1     = (const float*)d_in[4];
    const float* W2     = (const float*)d_in[5];
    const float* b2     = (const float*)d_in[6];
    const float* W3     = (const float*)d_in[7];
    const float* b3     = (const float*)d_in[8];
    float* out          = (float*)d_out;

    const int Brows = in_sizes[1] / (NPTS * 3);  // 1024
    encoder_kernel<<<dim3(Brows / 2), dim3(BDIM), 0, stream>>>(
        lg, coords, params, W1, b1, W2, b2, W3, b3, out);
}